// Round 5
// baseline (478.642 us; speedup 1.0000x reference)
//
#include <hip/hip_runtime.h>

#define HIDDEN 64
#define NB 32
#define HSTR 72   // LDS H-tile row stride in shorts: %8==0 (16B align for b128)

typedef __attribute__((ext_vector_type(8))) short bf16x8;
typedef __attribute__((ext_vector_type(4))) float f32x4;

// ---- bf16 helpers (RNE) ----
static __device__ __forceinline__ unsigned short f2bf(float x) {
    union { float f; unsigned u; } v; v.f = x;
    unsigned r = v.u + 0x7fffu + ((v.u >> 16) & 1u);
    return (unsigned short)(r >> 16);
}
static __device__ __forceinline__ float bf2f(unsigned short s) {
    union { unsigned u; float f; } v; v.u = ((unsigned)s) << 16;
    return v.f;
}

// ---------------------------------------------------------------------------
// CSR build: histogram -> single-block scan -> scatter (int2 {e, col}).
// ---------------------------------------------------------------------------
__global__ __launch_bounds__(256) void hist_kernel(
    const int* __restrict__ edge_index, int* __restrict__ counts, int E)
{
    int i = blockIdx.x * 256 + threadIdx.x;
    if (i < E) atomicAdd(&counts[edge_index[i]], 1);
}

// One block of 1024 threads scans all N counts (N=50k -> 49/thread).
__global__ __launch_bounds__(1024) void csr_scan_kernel(
    const int* __restrict__ counts, int* __restrict__ offsets,
    int* __restrict__ cursors, int N, int E)
{
    __shared__ int sums[1024];
    const int t = threadIdx.x;
    const int CH = (N + 1023) / 1024;
    const int base = t * CH;

    int s = 0;
    for (int i = 0; i < CH; ++i) {
        int idx = base + i;
        if (idx < N) s += counts[idx];
    }
    sums[t] = s;
    __syncthreads();
    for (int off = 1; off < 1024; off <<= 1) {
        int x = (t >= off) ? sums[t - off] : 0;
        __syncthreads();
        sums[t] += x;
        __syncthreads();
    }
    int run = sums[t] - s;            // exclusive prefix
    for (int i = 0; i < CH; ++i) {
        int idx = base + i;
        if (idx < N) {
            offsets[idx] = run;
            cursors[idx] = run;
            run += counts[idx];
        }
    }
    if (t == 0) offsets[N] = E;
}

__global__ __launch_bounds__(256) void scatter_kernel(
    const int* __restrict__ edge_index, int* __restrict__ cursors,
    int2* __restrict__ pc, int E)
{
    int i = blockIdx.x * 256 + threadIdx.x;
    if (i < E) {
        int pos = atomicAdd(&cursors[edge_index[i]], 1);
        pc[pos] = make_int2(i, edge_index[E + i]);   // {edge id, source col}
    }
}

// ---------------------------------------------------------------------------
// Phase A (MFMA, EDGE order — no perm gather): per-edge MLP weights.
// Output layout: W[e][0..63] = scalar-MLP weights, W[e][64..127] = vector-MLP
// weights (bf16) — one 256 B row per edge, full-granule under random reads.
// ---------------------------------------------------------------------------
__global__ __launch_bounds__(256) void mlp_mfma_kernel(
    const float* __restrict__ edge_length,   // [E,32]
    const float* __restrict__ sw1, const float* __restrict__ sb1,
    const float* __restrict__ sw2, const float* __restrict__ sb2,
    const float* __restrict__ vw1, const float* __restrict__ vb1,
    const float* __restrict__ vw2, const float* __restrict__ vb2,
    unsigned short* __restrict__ W,          // [E,128] bf16
    int E, int nchunks)
{
    __shared__ short Hs[4][64 * HSTR];       // per-wave staging (9216 B each)

    const int t    = threadIdx.x;
    const int lane = t & 63;
    const int wid  = t >> 6;
    const int quad = lane >> 4;
    const int l16  = lane & 15;
    short* Hw = Hs[wid];

    const float* w1p[2] = {sw1, vw1};
    const float* b1p[2] = {sb1, vb1};
    const float* w2p[2] = {sw2, vw2};
    const float* b2p[2] = {sb2, vb2};

    // ---- weight B-frags resident in VGPRs (once per wave) ----
    bf16x8 w1f[2][4];            // [mlp][ntile]
    bf16x8 w2f[2][2][4];         // [mlp][kstep][ntile]
    float  b1v[2][4], b2v[2][4];
    #pragma unroll
    for (int m = 0; m < 2; ++m) {
        #pragma unroll
        for (int nt = 0; nt < 4; ++nt) {
            const int col = nt * 16 + l16;
            #pragma unroll
            for (int j = 0; j < 8; ++j)
                w1f[m][nt][j] = (short)f2bf(w1p[m][(quad * 8 + j) * HIDDEN + col]);
            #pragma unroll
            for (int kk = 0; kk < 2; ++kk) {
                #pragma unroll
                for (int j = 0; j < 8; ++j)
                    w2f[m][kk][nt][j] = (short)f2bf(w2p[m][(kk * 32 + quad * 8 + j) * HIDDEN + col]);
            }
            b1v[m][nt] = b1p[m][col];
            b2v[m][nt] = b2p[m][col];
        }
    }

    const int wave_g = blockIdx.x * 4 + wid;
    const int nwaves = gridDim.x * 4;

    for (int c = wave_g; c < nchunks; c += nwaves) {
        const int j0 = c * 64;

        // ---- A-frags: 64 consecutive edges x 32 basis, coalesced ----
        bf16x8 af[4];
        #pragma unroll
        for (int mt = 0; mt < 4; ++mt) {
            int e = j0 + mt * 16 + l16;
            if (e >= E) e = E - 1;
            const float* r = edge_length + (size_t)e * NB + quad * 8;
            float4 u0 = *(const float4*)r;
            float4 u1 = *(const float4*)(r + 4);
            af[mt][0] = (short)f2bf(u0.x); af[mt][1] = (short)f2bf(u0.y);
            af[mt][2] = (short)f2bf(u0.z); af[mt][3] = (short)f2bf(u0.w);
            af[mt][4] = (short)f2bf(u1.x); af[mt][5] = (short)f2bf(u1.y);
            af[mt][6] = (short)f2bf(u1.z); af[mt][7] = (short)f2bf(u1.w);
        }

        #pragma unroll
        for (int m = 0; m < 2; ++m) {
            // ---- layer 1 + SiLU -> LDS bf16 ----
            #pragma unroll
            for (int mt = 0; mt < 4; ++mt) {
                #pragma unroll
                for (int nt = 0; nt < 4; ++nt) {
                    f32x4 cf = {b1v[m][nt], b1v[m][nt], b1v[m][nt], b1v[m][nt]};
                    cf = __builtin_amdgcn_mfma_f32_16x16x32_bf16(af[mt], w1f[m][nt], cf, 0, 0, 0);
                    #pragma unroll
                    for (int r4 = 0; r4 < 4; ++r4) {
                        float x = cf[r4];
                        x = x / (1.0f + __expf(-x));
                        const int row = mt * 16 + quad * 4 + r4;
                        Hw[row * HSTR + nt * 16 + l16] = (short)f2bf(x);
                    }
                }
            }

            // ---- layer 2 -> LDS bf16 ----
            #pragma unroll
            for (int mt = 0; mt < 4; ++mt) {
                const int arow = mt * 16 + l16;
                bf16x8 a0 = *(const bf16x8*)(Hw + arow * HSTR + quad * 8);
                bf16x8 a1 = *(const bf16x8*)(Hw + arow * HSTR + 32 + quad * 8);
                #pragma unroll
                for (int nt = 0; nt < 4; ++nt) {
                    f32x4 cf = {b2v[m][nt], b2v[m][nt], b2v[m][nt], b2v[m][nt]};
                    cf = __builtin_amdgcn_mfma_f32_16x16x32_bf16(a1, w2f[m][1][nt], cf, 0, 0, 0);
                    cf = __builtin_amdgcn_mfma_f32_16x16x32_bf16(a0, w2f[m][0][nt], cf, 0, 0, 0);
                    #pragma unroll
                    for (int r4 = 0; r4 < 4; ++r4) {
                        const int row = mt * 16 + quad * 4 + r4;
                        Hw[row * HSTR + nt * 16 + l16] = (short)f2bf(cf[r4]);
                    }
                }
            }

            // ---- store: 8 lanes per edge row, 16 B/lane, half-row m ----
            #pragma unroll
            for (int i = 0; i < 8; ++i) {
                const int row = i * 8 + (lane >> 3);
                bf16x8 v = *(const bf16x8*)(Hw + row * HSTR + (lane & 7) * 8);
                if (j0 + row < E)
                    *(bf16x8*)(W + (size_t)(j0 + row) * 128 + m * 64 + (lane & 7) * 8) = v;
            }
        }
    }
}

// ---------------------------------------------------------------------------
// Phase B: one wave per destination node; lane = channel. 1-deep software
// pipeline: prefetch edge j+1's weights/features while accumulating edge j.
// ---------------------------------------------------------------------------
__global__ __launch_bounds__(256) void node_kernel(
    const float* __restrict__ scalar,       // [N,64]
    const float* __restrict__ vector,       // [N,3,64]
    const int* __restrict__ offsets,        // [N+1]
    const int2* __restrict__ pc,            // [E] {e, col}, CSR order
    const unsigned short* __restrict__ W,   // [E,128] bf16
    float* __restrict__ out_scalar,         // [N,64]
    float* __restrict__ out_vector,         // [N,3,64]
    int N)
{
    const int lane = threadIdx.x & 63;
    const int wave = blockIdx.x * 4 + (threadIdx.x >> 6);
    const int nw   = gridDim.x * 4;

    for (int n = wave; n < N; n += nw) {
        const int beg = offsets[n];
        const int end = offsets[n + 1];

        float as = 0.0f, a0 = 0.0f, a1 = 0.0f, a2 = 0.0f;

        float ws = 0, wv = 0, s = 0, v0 = 0, v1 = 0, v2 = 0;
        if (beg < end) {
            const int2 p = pc[beg];
            const unsigned short* wp = W + (size_t)p.x * 128;
            ws = bf2f(wp[lane]); wv = bf2f(wp[64 + lane]);
            const float* sp = scalar + (size_t)p.y * HIDDEN;
            const float* vp = vector + (size_t)p.y * 3 * HIDDEN;
            s = sp[lane]; v0 = vp[lane]; v1 = vp[64 + lane]; v2 = vp[128 + lane];
        }

        for (int j = beg; j < end; ++j) {
            const int jn = (j + 1 < end) ? j + 1 : j;
            const int2 p = pc[jn];
            const unsigned short* wp = W + (size_t)p.x * 128;
            const float wsn = bf2f(wp[lane]);
            const float wvn = bf2f(wp[64 + lane]);
            const float* sp = scalar + (size_t)p.y * HIDDEN;
            const float* vp = vector + (size_t)p.y * 3 * HIDDEN;
            const float sn  = sp[lane];
            const float v0n = vp[lane];
            const float v1n = vp[64 + lane];
            const float v2n = vp[128 + lane];

            as = fmaf(s,  ws, as);
            a0 = fmaf(v0, wv, a0);
            a1 = fmaf(v1, wv, a1);
            a2 = fmaf(v2, wv, a2);

            ws = wsn; wv = wvn; s = sn; v0 = v0n; v1 = v1n; v2 = v2n;
        }

        out_scalar[(size_t)n * HIDDEN + lane] = as;
        float* ov = out_vector + (size_t)n * 3 * HIDDEN;
        ov[lane]       = a0;
        ov[64 + lane]  = a1;
        ov[128 + lane] = a2;
    }
}

extern "C" void kernel_launch(void* const* d_in, const int* in_sizes, int n_in,
                              void* d_out, int out_size, void* d_ws, size_t ws_size,
                              hipStream_t stream) {
    const float* scalar      = (const float*)d_in[0];
    const float* vector      = (const float*)d_in[1];
    // d_in[2] = edge_sh (unused by reference)
    const float* edge_length = (const float*)d_in[3];
    const int*   edge_index  = (const int*)d_in[4];
    const float* sw1 = (const float*)d_in[5];
    const float* sb1 = (const float*)d_in[6];
    const float* sw2 = (const float*)d_in[7];
    const float* sb2 = (const float*)d_in[8];
    const float* vw1 = (const float*)d_in[9];
    const float* vb1 = (const float*)d_in[10];
    const float* vw2 = (const float*)d_in[11];
    const float* vb2 = (const float*)d_in[12];

    const int N = in_sizes[0] / HIDDEN;       // 50000
    const int E = in_sizes[4] / 2;            // 500000

    float* out_scalar = (float*)d_out;
    float* out_vector = (float*)d_out + (size_t)N * HIDDEN;

    // ---- workspace layout ----
    unsigned short* W = (unsigned short*)d_ws;                 // [E,128] bf16 = 128 MB
    int* ib = (int*)((char*)d_ws + (size_t)E * 128 * 2);
    int* counts  = ib;                        // [N]
    int* offsets = ib + N;                    // [N+1]
    int* cursors = ib + 2 * N + 1;            // [N]
    int2* pc     = (int2*)(ib + 3 * N + 2);   // [E] (8B aligned: offset even)

    hipMemsetAsync(counts, 0, (size_t)N * sizeof(int), stream);

    const int egrid = (E + 255) / 256;

    // Phase A is CSR-independent: pure streaming MFMA MLP in edge order.
    const int nchunks = (E + 63) / 64;
    mlp_mfma_kernel<<<512, 256, 0, stream>>>(
        edge_length,
        sw1, sb1, sw2, sb2, vw1, vb1, vw2, vb2,
        W, E, nchunks);

    // CSR build
    hist_kernel<<<egrid, 256, 0, stream>>>(edge_index, counts, E);
    csr_scan_kernel<<<1, 1024, 0, stream>>>(counts, offsets, cursors, N, E);
    scatter_kernel<<<egrid, 256, 0, stream>>>(edge_index, cursors, pc, E);

    // Phase B: wave per node
    const int ngrid = (N + 3) / 4;
    node_kernel<<<ngrid, 256, 0, stream>>>(
        scalar, vector, offsets, pc, W,
        out_scalar, out_vector, N);
}

// Round 7
// 335.400 us; speedup vs baseline: 1.4271x; 1.4271x over previous
//
#include <hip/hip_runtime.h>

#define HIDDEN 64
#define NB 32
#define SCAN_BLOCK 1024
#define HSTR 72   // LDS H-tile row stride in shorts: %8==0 (16B align for b128)

typedef __attribute__((ext_vector_type(8))) short bf16x8;
typedef __attribute__((ext_vector_type(4))) float f32x4;

// ---- bf16 helpers (RNE) ----
static __device__ __forceinline__ unsigned short f2bf(float x) {
    union { float f; unsigned u; } v; v.f = x;
    unsigned r = v.u + 0x7fffu + ((v.u >> 16) & 1u);
    return (unsigned short)(r >> 16);
}
static __device__ __forceinline__ float bf2f(unsigned short s) {
    union { unsigned u; float f; } v; v.u = ((unsigned)s) << 16;
    return v.f;
}

// ---------------------------------------------------------------------------
// Feature pack: feat[n][lane] = {scalar, v0, v1, v2} as bf16x4 (8 B).
// One dwordx2 gather per edge in phase B instead of four dword gathers.
// ---------------------------------------------------------------------------
__global__ __launch_bounds__(256) void featpack_kernel(
    const float* __restrict__ scalar,   // [N,64]
    const float* __restrict__ vector,   // [N,3,64]
    ushort4* __restrict__ feat,         // [N*64]
    int total)                          // N*64
{
    int i = blockIdx.x * 256 + threadIdx.x;
    if (i >= total) return;
    const int n = i >> 6, l = i & 63;
    const float* vp = vector + (size_t)n * 192 + l;
    ushort4 o;
    o.x = f2bf(scalar[i]);
    o.y = f2bf(vp[0]);
    o.z = f2bf(vp[64]);
    o.w = f2bf(vp[128]);
    feat[i] = o;
}

// ---------------------------------------------------------------------------
// CSR scan: 3-pass multi-block (round-4 structure; single-block scan was a
// 125 us serialization disaster in round 5).
// ---------------------------------------------------------------------------
__global__ __launch_bounds__(SCAN_BLOCK) void scan_pass1(
    const int* __restrict__ counts, int* __restrict__ partial,
    int* __restrict__ blocksums, int N)
{
    __shared__ int tmp[SCAN_BLOCK];
    const int t = threadIdx.x;
    const int gid = blockIdx.x * SCAN_BLOCK + t;
    int v = (gid < N) ? counts[gid] : 0;
    tmp[t] = v;
    __syncthreads();
    for (int off = 1; off < SCAN_BLOCK; off <<= 1) {
        int x = (t >= off) ? tmp[t - off] : 0;
        __syncthreads();
        tmp[t] += x;
        __syncthreads();
    }
    if (gid < N) partial[gid] = tmp[t] - v;
    if (t == SCAN_BLOCK - 1) blocksums[blockIdx.x] = tmp[t];
}

__global__ __launch_bounds__(64) void scan_pass2(int* __restrict__ blocksums, int nb)
{
    const int t = threadIdx.x;
    int v = (t < nb) ? blocksums[t] : 0;
    int s = v;
    #pragma unroll
    for (int off = 1; off < 64; off <<= 1) {
        int x = __shfl_up(s, off, 64);
        if (t >= off) s += x;
    }
    if (t < nb) blocksums[t] = s - v;   // exclusive
}

__global__ __launch_bounds__(SCAN_BLOCK) void scan_pass3(
    const int* __restrict__ partial, const int* __restrict__ blocksums,
    int* __restrict__ offsets, int* __restrict__ cursors, int N, int E)
{
    const int gid = blockIdx.x * SCAN_BLOCK + threadIdx.x;
    if (gid < N) {
        int o = partial[gid] + blocksums[blockIdx.x];
        offsets[gid] = o;
        cursors[gid] = o;
    }
    if (blockIdx.x == 0 && threadIdx.x == 0) offsets[N] = E;
}

__global__ __launch_bounds__(256) void scatter_kernel(
    const int* __restrict__ edge_index, int* __restrict__ cursors,
    int2* __restrict__ pc, int E)
{
    int i = blockIdx.x * 256 + threadIdx.x;
    if (i < E) {
        int pos = atomicAdd(&cursors[edge_index[i]], 1);
        pc[pos] = make_int2(i, edge_index[E + i]);   // {edge id, source col}
    }
}

// ---------------------------------------------------------------------------
// Phase A (MFMA, edge order) + fused histogram.
// W[e][0..63] = scalar-MLP weights, W[e][64..127] = vector-MLP weights (bf16).
// ---------------------------------------------------------------------------
__global__ __launch_bounds__(256) void mlp_mfma_kernel(
    const float* __restrict__ edge_length,   // [E,32]
    const int*   __restrict__ edge_index,    // [2,E] (rows used for hist)
    int* __restrict__ counts,                // [N] (pre-zeroed)
    const float* __restrict__ sw1, const float* __restrict__ sb1,
    const float* __restrict__ sw2, const float* __restrict__ sb2,
    const float* __restrict__ vw1, const float* __restrict__ vb1,
    const float* __restrict__ vw2, const float* __restrict__ vb2,
    unsigned short* __restrict__ W,          // [E,128] bf16
    int E, int nchunks)
{
    __shared__ short Hs[4][64 * HSTR];       // per-wave staging

    const int t    = threadIdx.x;
    const int lane = t & 63;
    const int wid  = t >> 6;
    const int quad = lane >> 4;
    const int l16  = lane & 15;
    short* Hw = Hs[wid];

    const float* w1p[2] = {sw1, vw1};
    const float* b1p[2] = {sb1, vb1};
    const float* w2p[2] = {sw2, vw2};
    const float* b2p[2] = {sb2, vb2};

    // ---- weight B-frags resident in VGPRs ----
    bf16x8 w1f[2][4];
    bf16x8 w2f[2][2][4];
    float  b1v[2][4], b2v[2][4];
    #pragma unroll
    for (int m = 0; m < 2; ++m) {
        #pragma unroll
        for (int nt = 0; nt < 4; ++nt) {
            const int col = nt * 16 + l16;
            #pragma unroll
            for (int j = 0; j < 8; ++j)
                w1f[m][nt][j] = (short)f2bf(w1p[m][(quad * 8 + j) * HIDDEN + col]);
            #pragma unroll
            for (int kk = 0; kk < 2; ++kk) {
                #pragma unroll
                for (int j = 0; j < 8; ++j)
                    w2f[m][kk][nt][j] = (short)f2bf(w2p[m][(kk * 32 + quad * 8 + j) * HIDDEN + col]);
            }
            b1v[m][nt] = b1p[m][col];
            b2v[m][nt] = b2p[m][col];
        }
    }

    const int wave_g = blockIdx.x * 4 + wid;
    const int nwaves = gridDim.x * 4;

    for (int c = wave_g; c < nchunks; c += nwaves) {
        const int j0 = c * 64;

        // fused histogram: one edge per lane
        {
            const int e = j0 + lane;
            if (e < E) atomicAdd(&counts[edge_index[e]], 1);
        }

        // ---- A-frags: 64 consecutive edges x 32 basis, coalesced ----
        bf16x8 af[4];
        #pragma unroll
        for (int mt = 0; mt < 4; ++mt) {
            int e = j0 + mt * 16 + l16;
            if (e >= E) e = E - 1;
            const float* r = edge_length + (size_t)e * NB + quad * 8;
            float4 u0 = *(const float4*)r;
            float4 u1 = *(const float4*)(r + 4);
            af[mt][0] = (short)f2bf(u0.x); af[mt][1] = (short)f2bf(u0.y);
            af[mt][2] = (short)f2bf(u0.z); af[mt][3] = (short)f2bf(u0.w);
            af[mt][4] = (short)f2bf(u1.x); af[mt][5] = (short)f2bf(u1.y);
            af[mt][6] = (short)f2bf(u1.z); af[mt][7] = (short)f2bf(u1.w);
        }

        #pragma unroll
        for (int m = 0; m < 2; ++m) {
            // ---- layer 1 + SiLU -> LDS bf16 ----
            #pragma unroll
            for (int mt = 0; mt < 4; ++mt) {
                #pragma unroll
                for (int nt = 0; nt < 4; ++nt) {
                    f32x4 cf = {b1v[m][nt], b1v[m][nt], b1v[m][nt], b1v[m][nt]};
                    cf = __builtin_amdgcn_mfma_f32_16x16x32_bf16(af[mt], w1f[m][nt], cf, 0, 0, 0);
                    #pragma unroll
                    for (int r4 = 0; r4 < 4; ++r4) {
                        float x = cf[r4];
                        x = x / (1.0f + __expf(-x));
                        const int row = mt * 16 + quad * 4 + r4;
                        Hw[row * HSTR + nt * 16 + l16] = (short)f2bf(x);
                    }
                }
            }

            // ---- layer 2 -> LDS bf16 ----
            #pragma unroll
            for (int mt = 0; mt < 4; ++mt) {
                const int arow = mt * 16 + l16;
                bf16x8 a0 = *(const bf16x8*)(Hw + arow * HSTR + quad * 8);
                bf16x8 a1 = *(const bf16x8*)(Hw + arow * HSTR + 32 + quad * 8);
                #pragma unroll
                for (int nt = 0; nt < 4; ++nt) {
                    f32x4 cf = {b2v[m][nt], b2v[m][nt], b2v[m][nt], b2v[m][nt]};
                    cf = __builtin_amdgcn_mfma_f32_16x16x32_bf16(a1, w2f[m][1][nt], cf, 0, 0, 0);
                    cf = __builtin_amdgcn_mfma_f32_16x16x32_bf16(a0, w2f[m][0][nt], cf, 0, 0, 0);
                    #pragma unroll
                    for (int r4 = 0; r4 < 4; ++r4) {
                        const int row = mt * 16 + quad * 4 + r4;
                        Hw[row * HSTR + nt * 16 + l16] = (short)f2bf(cf[r4]);
                    }
                }
            }

            // ---- store: 8 lanes per edge row, 16 B/lane ----
            #pragma unroll
            for (int i = 0; i < 8; ++i) {
                const int row = i * 8 + (lane >> 3);
                bf16x8 v = *(const bf16x8*)(Hw + row * HSTR + (lane & 7) * 8);
                if (j0 + row < E)
                    *(bf16x8*)(W + (size_t)(j0 + row) * 128 + m * 64 + (lane & 7) * 8) = v;
            }
        }
    }
}

// ---------------------------------------------------------------------------
// Phase B (bf16 feat path): one wave per node; 1-deep pipeline.
// ---------------------------------------------------------------------------
__global__ __launch_bounds__(256) void node_kernel_feat(
    const ushort4* __restrict__ feat,       // [N*64] bf16 {s,v0,v1,v2}
    const int* __restrict__ offsets,        // [N+1]
    const int2* __restrict__ pc,            // [E] {e, col}
    const unsigned short* __restrict__ W,   // [E,128] bf16
    float* __restrict__ out_scalar,
    float* __restrict__ out_vector,
    int N)
{
    const int lane = threadIdx.x & 63;
    const int wave = blockIdx.x * 4 + (threadIdx.x >> 6);
    const int nw   = gridDim.x * 4;

    for (int n = wave; n < N; n += nw) {
        const int beg = offsets[n];
        const int end = offsets[n + 1];

        float as = 0.0f, a0 = 0.0f, a1 = 0.0f, a2 = 0.0f;
        float ws = 0, wv = 0, s = 0, v0 = 0, v1 = 0, v2 = 0;

        if (beg < end) {
            const int2 p = pc[beg];
            const unsigned short* wp = W + (size_t)p.x * 128;
            ws = bf2f(wp[lane]); wv = bf2f(wp[64 + lane]);
            const ushort4 f = feat[(size_t)p.y * 64 + lane];
            s = bf2f(f.x); v0 = bf2f(f.y); v1 = bf2f(f.z); v2 = bf2f(f.w);
        }

        for (int j = beg; j < end; ++j) {
            const int jn = (j + 1 < end) ? j + 1 : j;
            const int2 p = pc[jn];
            const unsigned short* wp = W + (size_t)p.x * 128;
            const float wsn = bf2f(wp[lane]);
            const float wvn = bf2f(wp[64 + lane]);
            const ushort4 f = feat[(size_t)p.y * 64 + lane];
            const float sn  = bf2f(f.x);
            const float v0n = bf2f(f.y);
            const float v1n = bf2f(f.z);
            const float v2n = bf2f(f.w);

            as = fmaf(s,  ws, as);
            a0 = fmaf(v0, wv, a0);
            a1 = fmaf(v1, wv, a1);
            a2 = fmaf(v2, wv, a2);

            ws = wsn; wv = wvn; s = sn; v0 = v0n; v1 = v1n; v2 = v2n;
        }

        out_scalar[(size_t)n * HIDDEN + lane] = as;
        float* ov = out_vector + (size_t)n * 3 * HIDDEN;
        ov[lane]       = a0;
        ov[64 + lane]  = a1;
        ov[128 + lane] = a2;
    }
}

// Fallback (fp32 feature gathers) if workspace can't hold the feat table.
__global__ __launch_bounds__(256) void node_kernel_f32(
    const float* __restrict__ scalar,
    const float* __restrict__ vector,
    const int* __restrict__ offsets,
    const int2* __restrict__ pc,
    const unsigned short* __restrict__ W,
    float* __restrict__ out_scalar,
    float* __restrict__ out_vector,
    int N)
{
    const int lane = threadIdx.x & 63;
    const int wave = blockIdx.x * 4 + (threadIdx.x >> 6);
    const int nw   = gridDim.x * 4;

    for (int n = wave; n < N; n += nw) {
        const int beg = offsets[n];
        const int end = offsets[n + 1];
        float as = 0.0f, a0 = 0.0f, a1 = 0.0f, a2 = 0.0f;
        for (int j = beg; j < end; ++j) {
            const int2 p = pc[j];
            const unsigned short* wp = W + (size_t)p.x * 128;
            const float w_s = bf2f(wp[lane]);
            const float w_v = bf2f(wp[64 + lane]);
            const float* sp = scalar + (size_t)p.y * HIDDEN;
            const float* vp = vector + (size_t)p.y * 3 * HIDDEN;
            as = fmaf(sp[lane],       w_s, as);
            a0 = fmaf(vp[lane],       w_v, a0);
            a1 = fmaf(vp[64 + lane],  w_v, a1);
            a2 = fmaf(vp[128 + lane], w_v, a2);
        }
        out_scalar[(size_t)n * HIDDEN + lane] = as;
        float* ov = out_vector + (size_t)n * 3 * HIDDEN;
        ov[lane]       = a0;
        ov[64 + lane]  = a1;
        ov[128 + lane] = a2;
    }
}

extern "C" void kernel_launch(void* const* d_in, const int* in_sizes, int n_in,
                              void* d_out, int out_size, void* d_ws, size_t ws_size,
                              hipStream_t stream) {
    const float* scalar      = (const float*)d_in[0];
    const float* vector      = (const float*)d_in[1];
    // d_in[2] = edge_sh (unused by reference)
    const float* edge_length = (const float*)d_in[3];
    const int*   edge_index  = (const int*)d_in[4];
    const float* sw1 = (const float*)d_in[5];
    const float* sb1 = (const float*)d_in[6];
    const float* sw2 = (const float*)d_in[7];
    const float* sb2 = (const float*)d_in[8];
    const float* vw1 = (const float*)d_in[9];
    const float* vb1 = (const float*)d_in[10];
    const float* vw2 = (const float*)d_in[11];
    const float* vb2 = (const float*)d_in[12];

    const int N = in_sizes[0] / HIDDEN;       // 50000
    const int E = in_sizes[4] / 2;            // 500000

    float* out_scalar = (float*)d_out;
    float* out_vector = (float*)d_out + (size_t)N * HIDDEN;

    // ---- workspace layout ----
    size_t off = 0;
    unsigned short* W = (unsigned short*)d_ws;           // [E,128] bf16 = 128 MB
    off += (size_t)E * 128 * 2;
    int2* pc = (int2*)((char*)d_ws + off);               // [E] = 4 MB
    off += (size_t)E * 8;
    int* ib = (int*)((char*)d_ws + off);
    int* counts    = ib;                                  // [N]
    int* partial   = ib + N;                              // [N]
    int* offsets   = ib + 2 * N;                          // [N+1]
    int* cursors   = ib + 3 * N + 1;                      // [N]
    int* blocksums = ib + 4 * N + 1;                      // [64]
    off += ((size_t)4 * N + 1 + 64) * 4;
    off = (off + 15) & ~(size_t)15;
    ushort4* feat = (ushort4*)((char*)d_ws + off);        // [N*64] = 25.6 MB
    const bool use_feat = (off + (size_t)N * 64 * 8) <= ws_size;

    hipMemsetAsync(counts, 0, (size_t)N * sizeof(int), stream);

    const int egrid = (E + 255) / 256;

    if (use_feat) {
        const int total = N * 64;
        featpack_kernel<<<(total + 255) / 256, 256, 0, stream>>>(
            scalar, vector, feat, total);
    }

    // Phase A (+ fused histogram), edge order.
    const int nchunks = (E + 63) / 64;
    mlp_mfma_kernel<<<512, 256, 0, stream>>>(
        edge_length, edge_index, counts,
        sw1, sb1, sw2, sb2, vw1, vb1, vw2, vb2,
        W, E, nchunks);

    // CSR scan (3-pass, multi-block) + scatter
    const int nb = (N + SCAN_BLOCK - 1) / SCAN_BLOCK;     // 49 (<=64 for pass2)
    scan_pass1<<<nb, SCAN_BLOCK, 0, stream>>>(counts, partial, blocksums, N);
    scan_pass2<<<1, 64, 0, stream>>>(blocksums, nb);
    scan_pass3<<<nb, SCAN_BLOCK, 0, stream>>>(partial, blocksums, offsets, cursors, N, E);
    scatter_kernel<<<egrid, 256, 0, stream>>>(edge_index, cursors, pc, E);

    // Phase B
    const int ngrid = (N + 3) / 4;
    if (use_feat) {
        node_kernel_feat<<<ngrid, 256, 0, stream>>>(
            feat, offsets, pc, W, out_scalar, out_vector, N);
    } else {
        node_kernel_f32<<<ngrid, 256, 0, stream>>>(
            scalar, vector, offsets, pc, W, out_scalar, out_vector, N);
    }
}